// Round 5
// baseline (115.756 us; speedup 1.0000x reference)
//
#include <hip/hip_runtime.h>

#define TPB 512

constexpr int NSEQ = 32768;
constexpr int C0   = 4096;               // output samples per block chunk (8 chunks/batch)
constexpr int COLW = 576;                // per-wave LDS column stride (floats) for the stretch
constexpr float SCG = 14.4269504089f;    // 10 * log2(e)

// Halos h_l = 2*h_{l+1}+3, h5=4 -> {221,109,53,25,11,4}
// Geometry: P5 = C0/32 + 8, P_{l-1} = 2*P_l + 8.
// C0=4096 padded level widths P: {2296,1144,568,280,136}; LE = {1148,572,284,140};
// L5 out contiguous stride 136; synthesis Sout {264,520,1032,2056}; final 4096.
//
// Phase plan (7 barriers): stage | L1 | L2 | L3 | {L4,L5,s5,s4 per-wave} | s3 | s2 | final
// Task counts: 287 | 286 | 284 | (35,34,66,65 per wave) | 516 | 514 | 512.
//
// THIS REVISION: uniform XOR bank swizzle on ALL LDS accesses:
//   byte ^= (byte>>3) & 0x70   (XOR bits [9:7] into [6:4])
// Rationale: analysis reads + synth writes have 32B lane stride -> lane l's 16B beat
// at byte 32l touches only every other 16B unit, lanes {l,l+4,..} share a bank quad
// -> ~16-way conflict (the 6-8M SQ_LDS_BANK_CONFLICT cycles). The XOR spreads beats
// across all 8 16B-units per 128B row; per quarter-wave <=2-3 lanes/unit (~free).
// Bijective within each 128B block; all accesses via one helper -> consistent.
// All float4 LDS accesses are 16B-aligned (bits[6:4] constant within a beat), so
// vector accesses stay contiguous. Buffers 512B-aligned, sizes 512B multiples.
//
// bufA: stage (4600) | L2-out (4576) | stretch cols (4608) | r2 (4128) -> 4608
// bufB: L1-out (4592) | L3-out cols / stretch (4608) | r1 (4112) -> 4608
// LDS = (4608+4608)*4 + bss = ~37 KB -> 4 blocks/CU (148 KB, 32 waves).
// Grid = 128 batches * 8 chunks = 1024 blocks = 4 * 256 CUs: ONE residency generation.

typedef float f2 __attribute__((ext_vector_type(2)));

__device__ __forceinline__ f2 sp(float x) { return (f2){x, x}; }
__device__ __forceinline__ f2 fma2(f2 a, f2 b, f2 c) { return __builtin_elementwise_fma(a, b, c); }

// ---- swizzled LDS access helpers (fidx = float index from 512B-aligned buffer base) ----
__device__ __forceinline__ int swzb(int fidx) {
    int b = fidx << 2;
    return b ^ ((b >> 3) & 0x70);
}
__device__ __forceinline__ float4 ldsw4(const float* buf, int fidx) {
    return *reinterpret_cast<const float4*>(reinterpret_cast<const char*>(buf) + swzb(fidx));
}
__device__ __forceinline__ void stsw4(float* buf, int fidx, float4 v) {
    *reinterpret_cast<float4*>(reinterpret_cast<char*>(buf) + swzb(fidx)) = v;
}
__device__ __forceinline__ void stsw1(float* buf, int fidx, float v) {
    *reinterpret_cast<float*>(reinterpret_cast<char*>(buf) + swzb(fidx)) = v;
}

__device__ __forceinline__ float rfl(float x) {
    return __builtin_bit_cast(float, __builtin_amdgcn_readfirstlane(__builtin_bit_cast(int, x)));
}

// Packed gate: y * (sigmoid(10(y-b)) + sigmoid(-10(y+b))) on both halves; tb = SCG*b.
__device__ __forceinline__ f2 gated2(f2 y, f2 tb) {
    f2 t1 = fma2(y, sp(-SCG), tb);
    f2 t2 = fma2(y, sp( SCG), tb);
    f2 s;
    s[0] = __builtin_amdgcn_rcpf(1.f + __builtin_amdgcn_exp2f(t1[0]))
         + __builtin_amdgcn_rcpf(1.f + __builtin_amdgcn_exp2f(t2[0]));
    s[1] = __builtin_amdgcn_rcpf(1.f + __builtin_amdgcn_exp2f(t1[1]))
         + __builtin_amdgcn_rcpf(1.f + __builtin_amdgcn_exp2f(t2[1]));
    return y * s;
}

// Block-wide analysis, r=8 per task, packed (yl,yh). klh[t] = (lp[t], hp[t]).
template<int LEin, int P, int PAIRS, int Nlev, bool EDGE, int OUTSTRIDE, int EOOFF>
__device__ __forceinline__ void analysis8(
    const float* __restrict__ inb, float* __restrict__ outb,
    const f2* __restrict__ klh, const float* __restrict__ bias, int outBase)
{
    constexpr int TPC = P / 8;
    constexpr int TOT = PAIRS * TPC;
    static_assert(TOT <= TPB, "analysis phase must be single-generation");
    const int task = threadIdx.x;
    if (task < TOT) {
        const int c  = task / TPC;
        const int i0 = (task - c * TPC) * 8;
        const int ie = c * (2 * LEin) + i0;            // E window base (float idx)
        const int io = ie + LEin;                      // O window base

        float a[12], b[12];
        reinterpret_cast<float4*>(a)[0] = ldsw4(inb, ie);
        reinterpret_cast<float4*>(a)[1] = ldsw4(inb, ie + 4);
        reinterpret_cast<float4*>(a)[2] = ldsw4(inb, ie + 8);
        reinterpret_cast<float4*>(b)[0] = ldsw4(inb, io);
        reinterpret_cast<float4*>(b)[1] = ldsw4(inb, io + 4);
        reinterpret_cast<float4*>(b)[2] = ldsw4(inb, io + 8);

        const int sw    = c & 1;
        const int ch_lp = 2 * c + sw;
        const int ch_hp = 2 * c + 1 - sw;
        const f2  tb    = (f2){bias[ch_lp], bias[ch_hp]};

        const int j0 = i0 >> 1;
        const int ol = ch_lp * OUTSTRIDE + j0;
        const int oh = ch_hp * OUTSTRIDE + j0;

#pragma unroll
        for (int par = 0; par < 2; ++par) {            // par=0 -> E plane, par=1 -> O plane
            f2 w[4];
#pragma unroll
            for (int k = 0; k < 4; ++k) {
                const int r = 2 * k + par;
                f2 y = (f2){0.f, 0.f};
#pragma unroll
                for (int u = 0; u < 4; ++u) {
                    y = fma2(sp(a[r + u]), klh[2 * u], y);
                    y = fma2(sp(b[r + u]), klh[2 * u + 1], y);
                }
                y = gated2(y, tb);
                if (EDGE) {
                    const bool ok = ((unsigned)(outBase + i0 + r) < (unsigned)Nlev);
                    y[0] = ok ? y[0] : 0.f;
                    y[1] = ok ? y[1] : 0.f;
                }
                w[k] = y;
            }
            stsw4(outb, ol + par * EOOFF, make_float4(w[0][0], w[1][0], w[2][0], w[3][0]));
            stsw4(outb, oh + par * EOOFF, make_float4(w[0][1], w[1][1], w[2][1], w[3][1]));
        }
    }
}

// Packed synthesis core: 8 outputs from ya/yb windows.
// o[0], o[7] scalar; pairs (o1,o2),(o3,o4),(o5,o6) packed with broadcast ya/yb.
// lrev[q] = (lp[6-2q], lp[7-2q]); hrev[q] = (hp[6-2q], hp[7-2q]).  JROFF: window offset.
template<int JROFF, bool EDGE>
__device__ __forceinline__ void synth_core(
    const float* __restrict__ ya, const float* __restrict__ yb,
    const f2* __restrict__ lrev, const f2* __restrict__ hrev,
    int gpos, int Nlev, float* __restrict__ o)
{
    f2 p1 = (f2){0.f, 0.f}, p2 = (f2){0.f, 0.f}, p3 = (f2){0.f, 0.f};
    float o0 = 0.f, o7 = 0.f;
#pragma unroll
    for (int q = 0; q < 4; ++q) {
        const f2 cl = lrev[q], ch = hrev[q];
        o0 = fmaf(ya[JROFF + q],     cl[1], o0);
        o0 = fmaf(yb[JROFF + q],     ch[1], o0);
        o7 = fmaf(ya[JROFF + 4 + q], cl[0], o7);
        o7 = fmaf(yb[JROFF + 4 + q], ch[0], o7);
        p1 = fma2(sp(ya[JROFF + 1 + q]), cl, p1);
        p1 = fma2(sp(yb[JROFF + 1 + q]), ch, p1);
        p2 = fma2(sp(ya[JROFF + 2 + q]), cl, p2);
        p2 = fma2(sp(yb[JROFF + 2 + q]), ch, p2);
        p3 = fma2(sp(ya[JROFF + 3 + q]), cl, p3);
        p3 = fma2(sp(yb[JROFF + 3 + q]), ch, p3);
    }
    o[0] = o0;    o[1] = p1[0]; o[2] = p1[1]; o[3] = p2[0];
    o[4] = p2[1]; o[5] = p3[0]; o[6] = p3[1]; o[7] = o7;
    if (EDGE) {
#pragma unroll
        for (int r = 0; r < 8; ++r) {
            const bool ok = ((unsigned)(gpos + r) < (unsigned)Nlev);
            o[r] = ok ? o[r] : 0.f;
        }
    }
}

// Block-wide synthesis r=8.  TOT may exceed TPB by a few: first TOT-TPB threads
// run a second task (compile-time unrolled, guarded).
template<int INSTRIDE, int Sout, int G, int Nlev, bool EDGE>
__device__ __forceinline__ void synthN(
    const float* __restrict__ inb, float* __restrict__ outb,
    const f2* __restrict__ lrev, const f2* __restrict__ hrev, int outBase)
{
    constexpr int TPG = Sout / 8;
    constexpr int TOT = G * TPG;
    static_assert(TOT <= 2 * TPB, "synth phase must fit in two generations");
#pragma unroll
    for (int t = threadIdx.x; t < TOT; t += TPB) {
        const int g   = t / TPG;
        const int nl0 = (t - g * TPG) * 8;
        const int sw  = g & 1;

        const int p0 = (2 * g + sw)     * INSTRIDE + nl0 / 2;   // lp channel
        const int p1 = (2 * g + 1 - sw) * INSTRIDE + nl0 / 2;   // hp channel
        float ya[8], yb[8];
        reinterpret_cast<float4*>(ya)[0] = ldsw4(inb, p0);
        reinterpret_cast<float4*>(ya)[1] = ldsw4(inb, p0 + 4);
        reinterpret_cast<float4*>(yb)[0] = ldsw4(inb, p1);
        reinterpret_cast<float4*>(yb)[1] = ldsw4(inb, p1 + 4);

        float o[8];
        synth_core<0, EDGE>(ya, yb, lrev, hrev, outBase + nl0, Nlev, o);
        const int op = g * Sout + nl0;
        stsw4(outb, op,     make_float4(o[0], o[1], o[2], o[3]));
        stsw4(outb, op + 4, make_float4(o[4], o[5], o[6], o[7]));
    }
}

// Per-wave barrier-free stretch: L4, L5, s5, s4 inside wave-column w.
template<bool EDGE>
__device__ __forceinline__ void stretch_wave(
    float* __restrict__ bufA, float* __restrict__ bufB,
    const f2* __restrict__ klh, const f2* __restrict__ lrev, const f2* __restrict__ hrev,
    const float* __restrict__ bss, int s)
{
    const int w    = threadIdx.x >> 6;       // subtree = L3-out channel
    const int lane = threadIdx.x & 63;
    const int cA   = w * COLW;               // column base in bufA (float idx)
    const int cB   = w * COLW;               // column base in bufB
    const int sww  = w & 1;

    // ---- L4 analysis (r=8): colB (E@0,O@284) -> colA local {sww,1-sww}, stride 280, EO 140
    if (lane < 35) {                          // P4/8 = 280/8
        const int i0 = lane * 8;
        const int ie = cB + i0;
        const int io = ie + 284;
        float a[12], b[12];
        reinterpret_cast<float4*>(a)[0] = ldsw4(bufB, ie);
        reinterpret_cast<float4*>(a)[1] = ldsw4(bufB, ie + 4);
        reinterpret_cast<float4*>(a)[2] = ldsw4(bufB, ie + 8);
        reinterpret_cast<float4*>(b)[0] = ldsw4(bufB, io);
        reinterpret_cast<float4*>(b)[1] = ldsw4(bufB, io + 4);
        reinterpret_cast<float4*>(b)[2] = ldsw4(bufB, io + 8);
        const f2 tb = (f2){bss[14 + 2 * w + sww], bss[14 + 2 * w + 1 - sww]};
        const int j0 = i0 >> 1;
        const int ol = cA + sww * 280 + j0;
        const int oh = cA + (1 - sww) * 280 + j0;
#pragma unroll
        for (int par = 0; par < 2; ++par) {
            f2 v[4];
#pragma unroll
            for (int k = 0; k < 4; ++k) {
                const int r = 2 * k + par;
                f2 y = (f2){0.f, 0.f};
#pragma unroll
                for (int u = 0; u < 4; ++u) {
                    y = fma2(sp(a[r + u]), klh[2 * u], y);
                    y = fma2(sp(b[r + u]), klh[2 * u + 1], y);
                }
                y = gated2(y, tb);
                if (EDGE) {
                    const bool ok = ((unsigned)(((s >> 4) - 11) + i0 + r) < 2048u);
                    y[0] = ok ? y[0] : 0.f;
                    y[1] = ok ? y[1] : 0.f;
                }
                v[k] = y;
            }
            stsw4(bufA, ol + par * 140, make_float4(v[0][0], v[1][0], v[2][0], v[3][0]));
            stsw4(bufA, oh + par * 140, make_float4(v[0][1], v[1][1], v[2][1], v[3][1]));
        }
    }

    // ---- L5 analysis (LAST, r=8): local l (global c=2w+l) -> colB contiguous stride 136
    // global out ch = 4w + {3l (lp), l+1 (hp)} since sw = c&1 = l.
    if (lane < 34) {                          // 2 ch * (136/8 = 17)
        const int l  = (lane >= 17) ? 1 : 0;
        const int i0 = (lane - 17 * l) * 8;
        const int ie = cA + l * 280 + i0;
        const int io = ie + 140;
        float a[12], b[12];
        reinterpret_cast<float4*>(a)[0] = ldsw4(bufA, ie);
        reinterpret_cast<float4*>(a)[1] = ldsw4(bufA, ie + 4);
        reinterpret_cast<float4*>(a)[2] = ldsw4(bufA, ie + 8);
        reinterpret_cast<float4*>(b)[0] = ldsw4(bufA, io);
        reinterpret_cast<float4*>(b)[1] = ldsw4(bufA, io + 4);
        reinterpret_cast<float4*>(b)[2] = ldsw4(bufA, io + 8);
        const int cg = 2 * w + l;
        const f2 tb = (f2){bss[30 + 2 * cg + l], bss[30 + 2 * cg + 1 - l]};
        f2 v[8];
#pragma unroll
        for (int r = 0; r < 8; ++r) {
            f2 y = (f2){0.f, 0.f};
#pragma unroll
            for (int u = 0; u < 4; ++u) {
                y = fma2(sp(a[r + u]), klh[2 * u], y);
                y = fma2(sp(b[r + u]), klh[2 * u + 1], y);
            }
            y = gated2(y, tb);
            if (EDGE) {
                const bool ok = ((unsigned)(((s >> 5) - 4) + i0 + r) < 1024u);
                y[0] = ok ? y[0] : 0.f;
                y[1] = ok ? y[1] : 0.f;
            }
            v[r] = y;
        }
        const int plo = cB + (3 * l) * 136 + i0;
        const int phi = cB + (l + 1) * 136 + i0;
        stsw4(bufB, plo,     make_float4(v[0][0], v[1][0], v[2][0], v[3][0]));
        stsw4(bufB, plo + 4, make_float4(v[4][0], v[5][0], v[6][0], v[7][0]));
        stsw4(bufB, phi,     make_float4(v[0][1], v[1][1], v[2][1], v[3][1]));
        stsw4(bufB, phi + 4, make_float4(v[4][1], v[5][1], v[6][1], v[7][1]));
    }

    // ---- s5: groups gl=0,1; L5 lp local = 3gl, hp local = gl+1; out colA local gl*264
    // 66 tasks: lanes 0,1 run a second task.
#pragma unroll
    for (int t = lane; t < 66; t += 64) {     // TPG = 264/8 = 33
        const int gl  = (t >= 33) ? 1 : 0;
        const int nl0 = (t - 33 * gl) * 8;
        const int p0 = cB + (3 * gl) * 136 + nl0 / 2;
        const int p1 = cB + (gl + 1) * 136 + nl0 / 2;
        float ya[8], yb[8];
        reinterpret_cast<float4*>(ya)[0] = ldsw4(bufB, p0);
        reinterpret_cast<float4*>(ya)[1] = ldsw4(bufB, p0 + 4);
        reinterpret_cast<float4*>(yb)[0] = ldsw4(bufB, p1);
        reinterpret_cast<float4*>(yb)[1] = ldsw4(bufB, p1 + 4);
        float o[8];
        synth_core<0, EDGE>(ya, yb, lrev, hrev, ((s >> 4) - 4) + nl0, 2048, o);
        const int op = cA + gl * 264 + nl0;
        stsw4(bufA, op,     make_float4(o[0], o[1], o[2], o[3]));
        stsw4(bufA, op + 4, make_float4(o[4], o[5], o[6], o[7]));
    }

    // ---- s4: group g = w; r4 lp local = sww; out r3 colB (520 floats @ col base)
    // 65 tasks: lane 0 runs a second task.
#pragma unroll
    for (int t = lane; t < 65; t += 64) {     // TPG = 520/8
        const int nl0 = t * 8;
        const int p0 = cA + sww * 264 + nl0 / 2;
        const int p1 = cA + (1 - sww) * 264 + nl0 / 2;
        float ya[8], yb[8];
        reinterpret_cast<float4*>(ya)[0] = ldsw4(bufA, p0);
        reinterpret_cast<float4*>(ya)[1] = ldsw4(bufA, p0 + 4);
        reinterpret_cast<float4*>(yb)[0] = ldsw4(bufA, p1);
        reinterpret_cast<float4*>(yb)[1] = ldsw4(bufA, p1 + 4);
        float o[8];
        synth_core<0, EDGE>(ya, yb, lrev, hrev, ((s >> 3) - 4) + nl0, 4096, o);
        stsw4(bufB, cB + nl0,     make_float4(o[0], o[1], o[2], o[3]));
        stsw4(bufB, cB + nl0 + 4, make_float4(o[4], o[5], o[6], o[7]));
    }
}

template<bool EDGE>
__device__ __forceinline__ void run_chunk(
    const float* __restrict__ xb, float* __restrict__ ob, int s,
    float* __restrict__ bufA, float* __restrict__ bufB,
    const f2* __restrict__ klh, const f2* __restrict__ lrev, const f2* __restrict__ hrev,
    const float* __restrict__ bss)
{
    const int tid = threadIdx.x;

    // Stage x window, base s-221: E[j]=x[base+2j] (idx j), O[j]=x[base+2j+1] (idx 2300+j)
    {
        const int base = s - 221;
#pragma unroll
        for (int k = 0; k < 5; ++k) {
            const int j = tid + TPB * k;
            if (j < 2300) {
                const int g0 = base + 2 * j;
                float e, o;
                if (EDGE) {
                    e = ((unsigned)g0       < (unsigned)NSEQ) ? xb[g0]     : 0.f;
                    o = ((unsigned)(g0 + 1) < (unsigned)NSEQ) ? xb[g0 + 1] : 0.f;
                } else {
                    e = xb[g0];
                    o = xb[g0 + 1];
                }
                stsw1(bufA, j,        e);
                stsw1(bufA, 2300 + j, o);
            }
        }
    }
    __syncthreads();

    // ---- block-wide analysis L1..L3 (r=8; L3 writes wave columns); tasks 287,286,284 ----
    analysis8<2300, 2296, 1, 16384, EDGE, 2296, 1148>(bufA, bufB, klh, bss + 0, (s >> 1) - 109);
    __syncthreads();
    analysis8<1148, 1144, 2,  8192, EDGE, 1144,  572>(bufB, bufA, klh, bss + 2, (s >> 2) - 53);
    __syncthreads();
    analysis8< 572,  568, 4,  4096, EDGE, COLW,  284>(bufA, bufB, klh, bss + 6, (s >> 3) - 25);
    __syncthreads();

    // ---- barrier-free per-wave subtree: L4, L5, s5, s4 ----
    stretch_wave<EDGE>(bufA, bufB, klh, lrev, hrev, bss, s);
    __syncthreads();

    // ---- block-wide synthesis s3, s2; tasks 516, 514 ----
    synthN<COLW, 1032, 4,  8192, EDGE>(bufB, bufA, lrev, hrev, (s >> 2) - 4);   // r3 cols -> r2
    __syncthreads();
    synthN<1032, 2056, 2, 16384, EDGE>(bufA, bufB, lrev, hrev, (s >> 1) - 4);   // r2 -> r1
    __syncthreads();

    // ---- final level (G=1) straight to global; r1 in bufB stride 2056; 512 x 8 outputs ----
    {
        const int i0 = tid * 8;
        const int p0 = i0 / 2;                    // channel 0 = lp (16B aligned)
        const int p1 = p0 + 2056;                 // channel 1 = hp
        float ya[12], yb[12];
        reinterpret_cast<float4*>(ya)[0] = ldsw4(bufB, p0);
        reinterpret_cast<float4*>(ya)[1] = ldsw4(bufB, p0 + 4);
        reinterpret_cast<float4*>(ya)[2] = ldsw4(bufB, p0 + 8);
        reinterpret_cast<float4*>(yb)[0] = ldsw4(bufB, p1);
        reinterpret_cast<float4*>(yb)[1] = ldsw4(bufB, p1 + 4);
        reinterpret_cast<float4*>(yb)[2] = ldsw4(bufB, p1 + 8);
        float o[8];
        synth_core<2, false>(ya, yb, lrev, hrev, 0, 1 << 30, o);
        *reinterpret_cast<float4*>(ob + i0)     = make_float4(o[0], o[1], o[2], o[3]);
        *reinterpret_cast<float4*>(ob + i0 + 4) = make_float4(o[4], o[5], o[6], o[7]);
    }
}

__global__ __launch_bounds__(TPB, 8) void wpt_fused(
    const float* __restrict__ x,
    const float* __restrict__ K1, const float* __restrict__ K2,
    const float* __restrict__ K3, const float* __restrict__ K4,
    const float* __restrict__ K5,
    const float* __restrict__ B1, const float* __restrict__ B2,
    const float* __restrict__ B3, const float* __restrict__ B4,
    const float* __restrict__ B5,
    float* __restrict__ out)
{
    // 512B alignment so the bank-swizzle key bits ([9:7] of the buffer-relative byte
    // offset) line up with absolute LDS banks; sizes are 512B multiples.
    __shared__ __attribute__((aligned(512))) float bufA[4608];
    __shared__ __attribute__((aligned(512))) float bufB[4608];
    __shared__ float bss[62];

    const int tid   = threadIdx.x;
    const int batch = blockIdx.x >> 3;
    const int cid   = blockIdx.x & 7;
    const int s     = cid * C0;

    // Filters in SGPRs: K1 = [lp | hp]; every level's rows are one of these two.
    float lp[8], hp[8];
#pragma unroll
    for (int t = 0; t < 8; ++t) {
        lp[t] = rfl(K1[t]);
        hp[t] = rfl(K1[8 + t]);
    }
    // Packed coefficient tables for pk_fma paths.
    f2 klh[8], lrev[4], hrev[4];
#pragma unroll
    for (int t = 0; t < 8; ++t) klh[t] = (f2){lp[t], hp[t]};
#pragma unroll
    for (int q = 0; q < 4; ++q) {
        lrev[q] = (f2){lp[6 - 2 * q], lp[7 - 2 * q]};
        hrev[q] = (f2){hp[6 - 2 * q], hp[7 - 2 * q]};
    }

    // Biases (pre-scaled by 10*log2(e)); 62 total, single pass with TPB=512
    {
        const float* bin[5] = {B1, B2, B3, B4, B5};
        const int boff[5] = {0, 2, 6, 14, 30};
#pragma unroll
        for (int l = 0; l < 5; ++l)
            for (int i = tid; i < (2 << l); i += TPB) bss[boff[l] + i] = SCG * bin[l][i];
    }

    const float* xb = x + batch * NSEQ;
    float* ob = out + batch * NSEQ + s;

    if (cid == 0 || cid == 7)
        run_chunk<true >(xb, ob, s, bufA, bufB, klh, lrev, hrev, bss);
    else
        run_chunk<false>(xb, ob, s, bufA, bufB, klh, lrev, hrev, bss);
}

extern "C" void kernel_launch(void* const* d_in, const int* in_sizes, int n_in,
                              void* d_out, int out_size, void* d_ws, size_t ws_size,
                              hipStream_t stream) {
    const int nbatch = in_sizes[0] / NSEQ;
    wpt_fused<<<dim3(nbatch * (NSEQ / C0)), dim3(TPB), 0, stream>>>(
        (const float*)d_in[0],
        (const float*)d_in[1], (const float*)d_in[2],
        (const float*)d_in[3], (const float*)d_in[4],
        (const float*)d_in[5],
        (const float*)d_in[6], (const float*)d_in[7],
        (const float*)d_in[8], (const float*)d_in[9],
        (const float*)d_in[10],
        (float*)d_out);
}

// Round 6
// 111.944 us; speedup vs baseline: 1.0341x; 1.0341x over previous
//
#include <hip/hip_runtime.h>

#define TPB 512

constexpr int NSEQ = 32768;
constexpr int C0   = 4096;               // output samples per block chunk (8 chunks/batch)
constexpr float SCG = 14.4269504089f;    // 10 * log2(e)

// Halos h_l = 2*h_{l+1}+3, h5=4 -> {221,109,53,25,11,4}
// Geometry: P5 = C0/32 + 8, P_{l-1} = 2*P_l + 8.
// C0=4096 padded level widths P: {2296,1144,568,280,136}; E/O halves {1148,572,284,140};
// L5 out contiguous stride 136; synthesis Sout {264,520,1032,2056}; final 4096.
//
// ALL phases block-wide (R6: stretch re-densified — per-wave version wasted ~2x
// wave-inst at <=35/64 active lanes; barriers are cheap, LDS issue slots are not).
// 10 barriers: stage|L1|L2|L3|L4|L5|s5|s4|s3|s2|final.
// Task counts: 1151 | 287 286 284 280 272 | 528 520 516 514 | 512.
//
// Ping-pong: stage->A, L1 A->B, L2 B->A, L3 A->B, L4 B->A, L5 A->B,
//            s5 B->A, s4 A->B, s3 B->A, s2 A->B, final B->global.
// bufA: stage E@0(2300,pad 2304) O@2304(2300)=4604 | L2(4576) | L4(4480) | r4(4224) | r2(4128)
// bufB: L1(4592) | L3(4544) | L5(4352) | r3(4160) | r1(4112)
// LDS = (4608+4608+62)*4 = 37112 B -> 4 blocks/CU (32 waves).
// Grid = 128 batches * 8 chunks = 1024 blocks = 4 * 256 CUs: one residency generation.

typedef float f2 __attribute__((ext_vector_type(2)));

__device__ __forceinline__ f2 sp(float x) { return (f2){x, x}; }
__device__ __forceinline__ f2 fma2(f2 a, f2 b, f2 c) { return __builtin_elementwise_fma(a, b, c); }

__device__ __forceinline__ float4 ldf4(const float* p) { return *reinterpret_cast<const float4*>(p); }
__device__ __forceinline__ void   stf4(float* p, const float4 v) { *reinterpret_cast<float4*>(p) = v; }

__device__ __forceinline__ float rfl(float x) {
    return __builtin_bit_cast(float, __builtin_amdgcn_readfirstlane(__builtin_bit_cast(int, x)));
}

// Packed gate: y * (sigmoid(10(y-b)) + sigmoid(-10(y+b))) on both halves; tb = SCG*b.
__device__ __forceinline__ f2 gated2(f2 y, f2 tb) {
    f2 t1 = fma2(y, sp(-SCG), tb);
    f2 t2 = fma2(y, sp( SCG), tb);
    f2 s;
    s[0] = __builtin_amdgcn_rcpf(1.f + __builtin_amdgcn_exp2f(t1[0]))
         + __builtin_amdgcn_rcpf(1.f + __builtin_amdgcn_exp2f(t2[0]));
    s[1] = __builtin_amdgcn_rcpf(1.f + __builtin_amdgcn_exp2f(t1[1]))
         + __builtin_amdgcn_rcpf(1.f + __builtin_amdgcn_exp2f(t2[1]));
    return y * s;
}

// Block-wide analysis, r=8 per task, packed (yl,yh). klh[t] = (lp[t], hp[t]).
// LEin = input E->O plane offset (input channel stride = 2*LEin).
// LAST=false: write E/O planes (OUTSTRIDE ch stride, EOOFF plane offset).
// LAST=true : write contiguous (OUTSTRIDE ch stride), for the s5 consumer.
template<int LEin, int P, int PAIRS, int Nlev, bool EDGE, int OUTSTRIDE, int EOOFF, bool LAST = false>
__device__ __forceinline__ void analysis8(
    const float* __restrict__ in, float* __restrict__ out,
    const f2* __restrict__ klh, const float* __restrict__ bias, int outBase)
{
    constexpr int TPC = P / 8;
    constexpr int TOT = PAIRS * TPC;
    static_assert(TOT <= TPB, "analysis phase must be single-generation");
    const int task = threadIdx.x;
    if (task < TOT) {
        const int c  = task / TPC;
        const int i0 = (task - c * TPC) * 8;

        const float* pe = in + c * (2 * LEin) + i0;
        const float* po = pe + LEin;
        float a[12], b[12];
        reinterpret_cast<float4*>(a)[0] = ldf4(pe);
        reinterpret_cast<float4*>(a)[1] = ldf4(pe + 4);
        reinterpret_cast<float4*>(a)[2] = ldf4(pe + 8);
        reinterpret_cast<float4*>(b)[0] = ldf4(po);
        reinterpret_cast<float4*>(b)[1] = ldf4(po + 4);
        reinterpret_cast<float4*>(b)[2] = ldf4(po + 8);

        const int sw    = c & 1;
        const int ch_lp = 2 * c + sw;
        const int ch_hp = 2 * c + 1 - sw;
        const f2  tb    = (f2){bias[ch_lp], bias[ch_hp]};

        if (LAST) {
            f2 v[8];
#pragma unroll
            for (int r = 0; r < 8; ++r) {
                f2 y = (f2){0.f, 0.f};
#pragma unroll
                for (int u = 0; u < 4; ++u) {
                    y = fma2(sp(a[r + u]), klh[2 * u], y);
                    y = fma2(sp(b[r + u]), klh[2 * u + 1], y);
                }
                y = gated2(y, tb);
                if (EDGE) {
                    const bool ok = ((unsigned)(outBase + i0 + r) < (unsigned)Nlev);
                    y[0] = ok ? y[0] : 0.f;
                    y[1] = ok ? y[1] : 0.f;
                }
                v[r] = y;
            }
            float* ol = out + ch_lp * OUTSTRIDE + i0;
            float* oh = out + ch_hp * OUTSTRIDE + i0;
            stf4(ol,     make_float4(v[0][0], v[1][0], v[2][0], v[3][0]));
            stf4(ol + 4, make_float4(v[4][0], v[5][0], v[6][0], v[7][0]));
            stf4(oh,     make_float4(v[0][1], v[1][1], v[2][1], v[3][1]));
            stf4(oh + 4, make_float4(v[4][1], v[5][1], v[6][1], v[7][1]));
        } else {
            const int j0 = i0 >> 1;
            float* ol = out + ch_lp * OUTSTRIDE + j0;
            float* oh = out + ch_hp * OUTSTRIDE + j0;
#pragma unroll
            for (int par = 0; par < 2; ++par) {        // par=0 -> E plane, par=1 -> O plane
                f2 w[4];
#pragma unroll
                for (int k = 0; k < 4; ++k) {
                    const int r = 2 * k + par;
                    f2 y = (f2){0.f, 0.f};
#pragma unroll
                    for (int u = 0; u < 4; ++u) {
                        y = fma2(sp(a[r + u]), klh[2 * u], y);
                        y = fma2(sp(b[r + u]), klh[2 * u + 1], y);
                    }
                    y = gated2(y, tb);
                    if (EDGE) {
                        const bool ok = ((unsigned)(outBase + i0 + 2 * k + par) < (unsigned)Nlev);
                        y[0] = ok ? y[0] : 0.f;
                        y[1] = ok ? y[1] : 0.f;
                    }
                    w[k] = y;
                }
                stf4(ol + par * EOOFF, make_float4(w[0][0], w[1][0], w[2][0], w[3][0]));
                stf4(oh + par * EOOFF, make_float4(w[0][1], w[1][1], w[2][1], w[3][1]));
            }
        }
    }
}

// Packed synthesis core: 8 outputs from ya/yb windows.
// lrev[q] = (lp[6-2q], lp[7-2q]); hrev[q] = (hp[6-2q], hp[7-2q]).  JROFF: window offset.
template<int JROFF, bool EDGE>
__device__ __forceinline__ void synth_core(
    const float* __restrict__ ya, const float* __restrict__ yb,
    const f2* __restrict__ lrev, const f2* __restrict__ hrev,
    int gpos, int Nlev, float* __restrict__ o)
{
    f2 p1 = (f2){0.f, 0.f}, p2 = (f2){0.f, 0.f}, p3 = (f2){0.f, 0.f};
    float o0 = 0.f, o7 = 0.f;
#pragma unroll
    for (int q = 0; q < 4; ++q) {
        const f2 cl = lrev[q], ch = hrev[q];
        o0 = fmaf(ya[JROFF + q],     cl[1], o0);
        o0 = fmaf(yb[JROFF + q],     ch[1], o0);
        o7 = fmaf(ya[JROFF + 4 + q], cl[0], o7);
        o7 = fmaf(yb[JROFF + 4 + q], ch[0], o7);
        p1 = fma2(sp(ya[JROFF + 1 + q]), cl, p1);
        p1 = fma2(sp(yb[JROFF + 1 + q]), ch, p1);
        p2 = fma2(sp(ya[JROFF + 2 + q]), cl, p2);
        p2 = fma2(sp(yb[JROFF + 2 + q]), ch, p2);
        p3 = fma2(sp(ya[JROFF + 3 + q]), cl, p3);
        p3 = fma2(sp(yb[JROFF + 3 + q]), ch, p3);
    }
    o[0] = o0;    o[1] = p1[0]; o[2] = p1[1]; o[3] = p2[0];
    o[4] = p2[1]; o[5] = p3[0]; o[6] = p3[1]; o[7] = o7;
    if (EDGE) {
#pragma unroll
        for (int r = 0; r < 8; ++r) {
            const bool ok = ((unsigned)(gpos + r) < (unsigned)Nlev);
            o[r] = ok ? o[r] : 0.f;
        }
    }
}

// Block-wide synthesis r=8.  TOT may exceed TPB: surplus threads run a second task.
template<int INSTRIDE, int Sout, int G, int Nlev, bool EDGE>
__device__ __forceinline__ void synthN(
    const float* __restrict__ in, float* __restrict__ out,
    const f2* __restrict__ lrev, const f2* __restrict__ hrev, int outBase)
{
    constexpr int TPG = Sout / 8;
    constexpr int TOT = G * TPG;
    static_assert(TOT <= 2 * TPB, "synth phase must fit in two generations");
#pragma unroll
    for (int t = threadIdx.x; t < TOT; t += TPB) {
        const int g   = t / TPG;
        const int nl0 = (t - g * TPG) * 8;
        const int sw  = g & 1;

        const float* p0 = in + (2 * g + sw)     * INSTRIDE + nl0 / 2;   // lp channel
        const float* p1 = in + (2 * g + 1 - sw) * INSTRIDE + nl0 / 2;   // hp channel
        float ya[8], yb[8];
        reinterpret_cast<float4*>(ya)[0] = ldf4(p0);
        reinterpret_cast<float4*>(ya)[1] = ldf4(p0 + 4);
        reinterpret_cast<float4*>(yb)[0] = ldf4(p1);
        reinterpret_cast<float4*>(yb)[1] = ldf4(p1 + 4);

        float o[8];
        synth_core<0, EDGE>(ya, yb, lrev, hrev, outBase + nl0, Nlev, o);
        float* op = out + g * Sout + nl0;
        stf4(op,     make_float4(o[0], o[1], o[2], o[3]));
        stf4(op + 4, make_float4(o[4], o[5], o[6], o[7]));
    }
}

template<bool EDGE>
__device__ __forceinline__ void run_chunk(
    const float* __restrict__ xb, float* __restrict__ ob, int s,
    float* __restrict__ bufA, float* __restrict__ bufB,
    const f2* __restrict__ klh, const f2* __restrict__ lrev, const f2* __restrict__ hrev,
    const float* __restrict__ bss)
{
    const int tid = threadIdx.x;

    // Stage: aligned float4 global loads, deinterleaved to E@0 / O@2304.
    // base = s-221 (== 3 mod 4), a0 = base-3 (16B aligned).  Quad q covers
    // x[a0+4q .. a0+4q+3] -> O[2q-2], E[2q-1], O[2q-1], E[2q]  (edge-guarded).
    {
        const int base = s - 221;
        const int a0   = base - 3;
#pragma unroll
        for (int k = 0; k < 3; ++k) {
            const int q = tid + TPB * k;
            if (q < 1151) {
                const int a = a0 + 4 * q;
                float4 v;
                if (!EDGE || (a >= 0 && a + 3 < NSEQ)) {
                    v = ldf4(xb + a);
                } else {
                    v.x = ((unsigned)(a)     < (unsigned)NSEQ) ? xb[a]     : 0.f;
                    v.y = ((unsigned)(a + 1) < (unsigned)NSEQ) ? xb[a + 1] : 0.f;
                    v.z = ((unsigned)(a + 2) < (unsigned)NSEQ) ? xb[a + 2] : 0.f;
                    v.w = ((unsigned)(a + 3) < (unsigned)NSEQ) ? xb[a + 3] : 0.f;
                }
                const int jo = 2 * q - 2;
                const int je = 2 * q - 1;
                if ((unsigned)jo       < 2300u) bufA[2304 + jo]     = v.x;  // O[2q-2]
                if ((unsigned)je       < 2300u) bufA[je]            = v.y;  // E[2q-1]
                if ((unsigned)(jo + 1) < 2300u) bufA[2304 + jo + 1] = v.z;  // O[2q-1]
                if ((unsigned)(je + 1) < 2300u) bufA[je + 1]        = v.w;  // E[2q]
            }
        }
    }
    __syncthreads();

    // ---- analysis L1..L5 (all block-wide, r=8); tasks 287,286,284,280,272 ----
    analysis8<2304, 2296,  1, 16384, EDGE, 2296, 1148>(bufA, bufB, klh, bss + 0,  (s >> 1) - 109);
    __syncthreads();
    analysis8<1148, 1144,  2,  8192, EDGE, 1144,  572>(bufB, bufA, klh, bss + 2,  (s >> 2) - 53);
    __syncthreads();
    analysis8< 572,  568,  4,  4096, EDGE,  568,  284>(bufA, bufB, klh, bss + 6,  (s >> 3) - 25);
    __syncthreads();
    analysis8< 284,  280,  8,  2048, EDGE,  280,  140>(bufB, bufA, klh, bss + 14, (s >> 4) - 11);
    __syncthreads();
    analysis8< 140,  136, 16,  1024, EDGE,  136,    0, true>(bufA, bufB, klh, bss + 30, (s >> 5) - 4);
    __syncthreads();

    // ---- synthesis s5..s2 (block-wide); tasks 528,520,516,514 ----
    synthN< 136,  264, 16,  2048, EDGE>(bufB, bufA, lrev, hrev, (s >> 4) - 4);   // L5 -> r4
    __syncthreads();
    synthN< 264,  520,  8,  4096, EDGE>(bufA, bufB, lrev, hrev, (s >> 3) - 4);   // r4 -> r3
    __syncthreads();
    synthN< 520, 1032,  4,  8192, EDGE>(bufB, bufA, lrev, hrev, (s >> 2) - 4);   // r3 -> r2
    __syncthreads();
    synthN<1032, 2056,  2, 16384, EDGE>(bufA, bufB, lrev, hrev, (s >> 1) - 4);   // r2 -> r1
    __syncthreads();

    // ---- final level (G=1) straight to global; r1 in bufB stride 2056; 512 x 8 ----
    {
        const int i0 = tid * 8;
        float ya[12], yb[12];
        {
            const float* p0 = bufB + i0 / 2;          // channel 0 = lp (16B aligned)
            const float* p1 = p0 + 2056;              // channel 1 = hp
            reinterpret_cast<float4*>(ya)[0] = ldf4(p0);
            reinterpret_cast<float4*>(ya)[1] = ldf4(p0 + 4);
            reinterpret_cast<float4*>(ya)[2] = ldf4(p0 + 8);
            reinterpret_cast<float4*>(yb)[0] = ldf4(p1);
            reinterpret_cast<float4*>(yb)[1] = ldf4(p1 + 4);
            reinterpret_cast<float4*>(yb)[2] = ldf4(p1 + 8);
        }
        float o[8];
        synth_core<2, false>(ya, yb, lrev, hrev, 0, 1 << 30, o);
        stf4(ob + i0,     make_float4(o[0], o[1], o[2], o[3]));
        stf4(ob + i0 + 4, make_float4(o[4], o[5], o[6], o[7]));
    }
}

__global__ __launch_bounds__(TPB, 8) void wpt_fused(
    const float* __restrict__ x,
    const float* __restrict__ K1, const float* __restrict__ K2,
    const float* __restrict__ K3, const float* __restrict__ K4,
    const float* __restrict__ K5,
    const float* __restrict__ B1, const float* __restrict__ B2,
    const float* __restrict__ B3, const float* __restrict__ B4,
    const float* __restrict__ B5,
    float* __restrict__ out)
{
    __shared__ __align__(16) float bufA[4608];
    __shared__ __align__(16) float bufB[4608];
    __shared__ float bss[62];

    const int tid   = threadIdx.x;
    const int batch = blockIdx.x >> 3;
    const int cid   = blockIdx.x & 7;
    const int s     = cid * C0;

    // Filters in SGPRs: K1 = [lp | hp]; every level's rows are one of these two.
    float lp[8], hp[8];
#pragma unroll
    for (int t = 0; t < 8; ++t) {
        lp[t] = rfl(K1[t]);
        hp[t] = rfl(K1[8 + t]);
    }
    // Packed coefficient tables for pk_fma paths.
    f2 klh[8], lrev[4], hrev[4];
#pragma unroll
    for (int t = 0; t < 8; ++t) klh[t] = (f2){lp[t], hp[t]};
#pragma unroll
    for (int q = 0; q < 4; ++q) {
        lrev[q] = (f2){lp[6 - 2 * q], lp[7 - 2 * q]};
        hrev[q] = (f2){hp[6 - 2 * q], hp[7 - 2 * q]};
    }

    // Biases (pre-scaled by 10*log2(e)); 62 total, single pass with TPB=512
    {
        const float* bin[5] = {B1, B2, B3, B4, B5};
        const int boff[5] = {0, 2, 6, 14, 30};
#pragma unroll
        for (int l = 0; l < 5; ++l)
            for (int i = tid; i < (2 << l); i += TPB) bss[boff[l] + i] = SCG * bin[l][i];
    }

    const float* xb = x + batch * NSEQ;
    float* ob = out + batch * NSEQ + s;

    if (cid == 0 || cid == 7)
        run_chunk<true >(xb, ob, s, bufA, bufB, klh, lrev, hrev, bss);
    else
        run_chunk<false>(xb, ob, s, bufA, bufB, klh, lrev, hrev, bss);
}

extern "C" void kernel_launch(void* const* d_in, const int* in_sizes, int n_in,
                              void* d_out, int out_size, void* d_ws, size_t ws_size,
                              hipStream_t stream) {
    const int nbatch = in_sizes[0] / NSEQ;
    wpt_fused<<<dim3(nbatch * (NSEQ / C0)), dim3(TPB), 0, stream>>>(
        (const float*)d_in[0],
        (const float*)d_in[1], (const float*)d_in[2],
        (const float*)d_in[3], (const float*)d_in[4],
        (const float*)d_in[5],
        (const float*)d_in[6], (const float*)d_in[7],
        (const float*)d_in[8], (const float*)d_in[9],
        (const float*)d_in[10],
        (float*)d_out);
}

// Round 7
// 111.137 us; speedup vs baseline: 1.0416x; 1.0073x over previous
//
#include <hip/hip_runtime.h>

#define TPB 256

constexpr int NSEQ = 32768;
constexpr int C0   = 4096;               // output samples per block chunk (8 chunks/batch)
constexpr float SCG = 14.4269504089f;    // 10 * log2(e)

// Halos h_l = 2*h_{l+1}+3, h5=4 -> {221,109,53,25,11,4}
// Geometry: P5 = C0/32 + 8, P_{l-1} = 2*P_l + 8.
// C0=4096 padded level widths P: {2296,1144,568,280,136}; E/O halves {1148,572,284,140};
// L5 out contiguous stride 136; synthesis Sout {264,520,1032,2056}; final 4096.
//
// R7: TPB=256, DUAL-TASK phases. Every phase has 272..528 tasks; thread handles
// tasks {tid, tid+256 (guarded/uncond), tid+512 (synth tail)}. Both tasks' LDS
// loads are issued BEFORE either compute -> each wave's stream interleaves
// ds_read issue with 2x VALU run (intra-wave LDS||VALU overlap), and 4-wave
// blocks give 4 independent barrier groups/CU with longer bodies (cross-wave
// drift). Rationale: measured wall ~ LDS-time + VALU-time (lockstep phase
// bursts); this restructures toward max() at constant total work.
// 10 barriers: stage|L1|L2|L3|L4|L5|s5|s4|s3|s2|final.
//
// Ping-pong: stage->A, L1 A->B, L2 B->A, L3 A->B, L4 B->A, L5 A->B,
//            s5 B->A, s4 A->B, s3 B->A, s2 A->B, final B->global.
// bufA: stage E@0(2304) O@2304(2300) | L2(4576) | L4(4480) | r4(4224) | r2(4128)
// bufB: L1(4592) | L3(4544) | L5(4352) | r3(4160) | r1(4112)
// LDS = (4608+4608+62)*4 = 37112 B -> 4 blocks/CU; 4 waves/block -> 16 waves/CU.
// launch_bounds(256,4) -> 128 VGPR/wave cap (dual-task liveness ~100).
// Grid = 128 batches * 8 chunks = 1024 blocks = 4 * 256 CUs: one generation.

typedef float f2 __attribute__((ext_vector_type(2)));

__device__ __forceinline__ f2 sp(float x) { return (f2){x, x}; }
__device__ __forceinline__ f2 fma2(f2 a, f2 b, f2 c) { return __builtin_elementwise_fma(a, b, c); }

__device__ __forceinline__ float4 ldf4(const float* p) { return *reinterpret_cast<const float4*>(p); }
__device__ __forceinline__ void   stf4(float* p, const float4 v) { *reinterpret_cast<float4*>(p) = v; }

__device__ __forceinline__ void ld12(float* d, const float* p) {
    reinterpret_cast<float4*>(d)[0] = ldf4(p);
    reinterpret_cast<float4*>(d)[1] = ldf4(p + 4);
    reinterpret_cast<float4*>(d)[2] = ldf4(p + 8);
}
__device__ __forceinline__ void ld8(float* d, const float* p) {
    reinterpret_cast<float4*>(d)[0] = ldf4(p);
    reinterpret_cast<float4*>(d)[1] = ldf4(p + 4);
}

__device__ __forceinline__ float rfl(float x) {
    return __builtin_bit_cast(float, __builtin_amdgcn_readfirstlane(__builtin_bit_cast(int, x)));
}

// Packed gate: y * (sigmoid(10(y-b)) + sigmoid(-10(y+b))) on both halves; tb = SCG*b.
__device__ __forceinline__ f2 gated2(f2 y, f2 tb) {
    f2 t1 = fma2(y, sp(-SCG), tb);
    f2 t2 = fma2(y, sp( SCG), tb);
    f2 s;
    s[0] = __builtin_amdgcn_rcpf(1.f + __builtin_amdgcn_exp2f(t1[0]))
         + __builtin_amdgcn_rcpf(1.f + __builtin_amdgcn_exp2f(t2[0]));
    s[1] = __builtin_amdgcn_rcpf(1.f + __builtin_amdgcn_exp2f(t1[1]))
         + __builtin_amdgcn_rcpf(1.f + __builtin_amdgcn_exp2f(t2[1]));
    return y * s;
}

// Compute+store for one analysis task (inputs already in registers).
template<int Nlev, bool EDGE, int OUTSTRIDE, int EOOFF, bool LAST>
__device__ __forceinline__ void analysis_cs(
    const float* __restrict__ a, const float* __restrict__ b, int c, int i0,
    float* __restrict__ out, const f2* __restrict__ klh,
    const float* __restrict__ bias, int outBase)
{
    const int sw    = c & 1;
    const int ch_lp = 2 * c + sw;
    const int ch_hp = 2 * c + 1 - sw;
    const f2  tb    = (f2){bias[ch_lp], bias[ch_hp]};

    if (LAST) {
        f2 v[8];
#pragma unroll
        for (int r = 0; r < 8; ++r) {
            f2 y = (f2){0.f, 0.f};
#pragma unroll
            for (int u = 0; u < 4; ++u) {
                y = fma2(sp(a[r + u]), klh[2 * u], y);
                y = fma2(sp(b[r + u]), klh[2 * u + 1], y);
            }
            y = gated2(y, tb);
            if (EDGE) {
                const bool ok = ((unsigned)(outBase + i0 + r) < (unsigned)Nlev);
                y[0] = ok ? y[0] : 0.f;
                y[1] = ok ? y[1] : 0.f;
            }
            v[r] = y;
        }
        float* ol = out + ch_lp * OUTSTRIDE + i0;
        float* oh = out + ch_hp * OUTSTRIDE + i0;
        stf4(ol,     make_float4(v[0][0], v[1][0], v[2][0], v[3][0]));
        stf4(ol + 4, make_float4(v[4][0], v[5][0], v[6][0], v[7][0]));
        stf4(oh,     make_float4(v[0][1], v[1][1], v[2][1], v[3][1]));
        stf4(oh + 4, make_float4(v[4][1], v[5][1], v[6][1], v[7][1]));
    } else {
        const int j0 = i0 >> 1;
        float* ol = out + ch_lp * OUTSTRIDE + j0;
        float* oh = out + ch_hp * OUTSTRIDE + j0;
#pragma unroll
        for (int par = 0; par < 2; ++par) {            // par=0 -> E plane, par=1 -> O plane
            f2 w[4];
#pragma unroll
            for (int k = 0; k < 4; ++k) {
                const int r = 2 * k + par;
                f2 y = (f2){0.f, 0.f};
#pragma unroll
                for (int u = 0; u < 4; ++u) {
                    y = fma2(sp(a[r + u]), klh[2 * u], y);
                    y = fma2(sp(b[r + u]), klh[2 * u + 1], y);
                }
                y = gated2(y, tb);
                if (EDGE) {
                    const bool ok = ((unsigned)(outBase + i0 + r) < (unsigned)Nlev);
                    y[0] = ok ? y[0] : 0.f;
                    y[1] = ok ? y[1] : 0.f;
                }
                w[k] = y;
            }
            stf4(ol + par * EOOFF, make_float4(w[0][0], w[1][0], w[2][0], w[3][0]));
            stf4(oh + par * EOOFF, make_float4(w[0][1], w[1][1], w[2][1], w[3][1]));
        }
    }
}

// Dual-task block-wide analysis (TOT in (TPB, 2*TPB]); loads for BOTH tasks
// issued before either compute.
template<int LEin, int P, int PAIRS, int Nlev, bool EDGE, int OUTSTRIDE, int EOOFF, bool LAST = false>
__device__ __forceinline__ void analysis8(
    const float* __restrict__ in, float* __restrict__ out,
    const f2* __restrict__ klh, const float* __restrict__ bias, int outBase)
{
    constexpr int TPC = P / 8;
    constexpr int TOT = PAIRS * TPC;
    static_assert(TOT > TPB && TOT <= 2 * TPB, "analysis must be dual-generation");
    const int t0 = threadIdx.x;
    const int t1 = t0 + TPB;
    const bool has1 = (t1 < TOT);

    const int c0 = t0 / TPC, i0 = (t0 - c0 * TPC) * 8;
    const int c1 = t1 / TPC, i1 = (t1 - c1 * TPC) * 8;

    float a0[12], b0[12], a1[12], b1[12];
    {
        const float* pe = in + c0 * (2 * LEin) + i0;
        ld12(a0, pe);
        ld12(b0, pe + LEin);
    }
    if (has1) {
        const float* pe = in + c1 * (2 * LEin) + i1;
        ld12(a1, pe);
        ld12(b1, pe + LEin);
    }
    analysis_cs<Nlev, EDGE, OUTSTRIDE, EOOFF, LAST>(a0, b0, c0, i0, out, klh, bias, outBase);
    if (has1)
        analysis_cs<Nlev, EDGE, OUTSTRIDE, EOOFF, LAST>(a1, b1, c1, i1, out, klh, bias, outBase);
}

// Packed synthesis core: 8 outputs from ya/yb windows.
// lrev[q] = (lp[6-2q], lp[7-2q]); hrev[q] = (hp[6-2q], hp[7-2q]).  JROFF: window offset.
template<int JROFF, bool EDGE>
__device__ __forceinline__ void synth_core(
    const float* __restrict__ ya, const float* __restrict__ yb,
    const f2* __restrict__ lrev, const f2* __restrict__ hrev,
    int gpos, int Nlev, float* __restrict__ o)
{
    f2 p1 = (f2){0.f, 0.f}, p2 = (f2){0.f, 0.f}, p3 = (f2){0.f, 0.f};
    float o0 = 0.f, o7 = 0.f;
#pragma unroll
    for (int q = 0; q < 4; ++q) {
        const f2 cl = lrev[q], ch = hrev[q];
        o0 = fmaf(ya[JROFF + q],     cl[1], o0);
        o0 = fmaf(yb[JROFF + q],     ch[1], o0);
        o7 = fmaf(ya[JROFF + 4 + q], cl[0], o7);
        o7 = fmaf(yb[JROFF + 4 + q], ch[0], o7);
        p1 = fma2(sp(ya[JROFF + 1 + q]), cl, p1);
        p1 = fma2(sp(yb[JROFF + 1 + q]), ch, p1);
        p2 = fma2(sp(ya[JROFF + 2 + q]), cl, p2);
        p2 = fma2(sp(yb[JROFF + 2 + q]), ch, p2);
        p3 = fma2(sp(ya[JROFF + 3 + q]), cl, p3);
        p3 = fma2(sp(yb[JROFF + 3 + q]), ch, p3);
    }
    o[0] = o0;    o[1] = p1[0]; o[2] = p1[1]; o[3] = p2[0];
    o[4] = p2[1]; o[5] = p3[0]; o[6] = p3[1]; o[7] = o7;
    if (EDGE) {
#pragma unroll
        for (int r = 0; r < 8; ++r) {
            const bool ok = ((unsigned)(gpos + r) < (unsigned)Nlev);
            o[r] = ok ? o[r] : 0.f;
        }
    }
}

// Compute+store for one synthesis task (inputs already in registers).
template<int Sout, int Nlev, bool EDGE>
__device__ __forceinline__ void synth_cs(
    const float* __restrict__ ya, const float* __restrict__ yb, int g, int nl0,
    float* __restrict__ out, const f2* __restrict__ lrev, const f2* __restrict__ hrev,
    int outBase)
{
    float o[8];
    synth_core<0, EDGE>(ya, yb, lrev, hrev, outBase + nl0, Nlev, o);
    float* op = out + g * Sout + nl0;
    stf4(op,     make_float4(o[0], o[1], o[2], o[3]));
    stf4(op + 4, make_float4(o[4], o[5], o[6], o[7]));
}

// Dual-task block-wide synthesis + small guarded tail (TOT in [2*TPB+2, 3*TPB]).
template<int INSTRIDE, int Sout, int G, int Nlev, bool EDGE>
__device__ __forceinline__ void synthN(
    const float* __restrict__ in, float* __restrict__ out,
    const f2* __restrict__ lrev, const f2* __restrict__ hrev, int outBase)
{
    constexpr int TPG = Sout / 8;
    constexpr int TOT = G * TPG;
    static_assert(TOT >= 2 * TPB && TOT <= 3 * TPB, "synth: two full + tail");
    const int t0 = threadIdx.x;
    const int t1 = t0 + TPB;                 // TOT >= 512+2 -> unconditional
    const int g0 = t0 / TPG, nl00 = (t0 - g0 * TPG) * 8;
    const int g1 = t1 / TPG, nl01 = (t1 - g1 * TPG) * 8;

    float ya0[8], yb0[8], ya1[8], yb1[8];
    {
        const int sw = g0 & 1;
        ld8(ya0, in + (2 * g0 + sw)     * INSTRIDE + nl00 / 2);
        ld8(yb0, in + (2 * g0 + 1 - sw) * INSTRIDE + nl00 / 2);
    }
    {
        const int sw = g1 & 1;
        ld8(ya1, in + (2 * g1 + sw)     * INSTRIDE + nl01 / 2);
        ld8(yb1, in + (2 * g1 + 1 - sw) * INSTRIDE + nl01 / 2);
    }
    synth_cs<Sout, Nlev, EDGE>(ya0, yb0, g0, nl00, out, lrev, hrev, outBase);
    synth_cs<Sout, Nlev, EDGE>(ya1, yb1, g1, nl01, out, lrev, hrev, outBase);

    const int t2 = t0 + 2 * TPB;             // tail: 2..16 threads
    if (t2 < TOT) {
        const int g2 = t2 / TPG, nl02 = (t2 - g2 * TPG) * 8;
        const int sw = g2 & 1;
        float ya2[8], yb2[8];
        ld8(ya2, in + (2 * g2 + sw)     * INSTRIDE + nl02 / 2);
        ld8(yb2, in + (2 * g2 + 1 - sw) * INSTRIDE + nl02 / 2);
        synth_cs<Sout, Nlev, EDGE>(ya2, yb2, g2, nl02, out, lrev, hrev, outBase);
    }
}

template<bool EDGE>
__device__ __forceinline__ void run_chunk(
    const float* __restrict__ xb, float* __restrict__ ob, int s,
    float* __restrict__ bufA, float* __restrict__ bufB,
    const f2* __restrict__ klh, const f2* __restrict__ lrev, const f2* __restrict__ hrev,
    const float* __restrict__ bss)
{
    const int tid = threadIdx.x;

    // Stage: aligned float4 global loads, deinterleaved to E@0 / O@2304.
    // base = s-221 (== 3 mod 4), a0 = base-3 (16B aligned).  Quad q covers
    // x[a0+4q .. a0+4q+3] -> O[2q-2], E[2q-1], O[2q-1], E[2q]  (edge-guarded).
    {
        const int base = s - 221;
        const int a0   = base - 3;
#pragma unroll
        for (int k = 0; k < 5; ++k) {
            const int q = tid + TPB * k;
            if (q < 1151) {
                const int a = a0 + 4 * q;
                float4 v;
                if (!EDGE || (a >= 0 && a + 3 < NSEQ)) {
                    v = ldf4(xb + a);
                } else {
                    v.x = ((unsigned)(a)     < (unsigned)NSEQ) ? xb[a]     : 0.f;
                    v.y = ((unsigned)(a + 1) < (unsigned)NSEQ) ? xb[a + 1] : 0.f;
                    v.z = ((unsigned)(a + 2) < (unsigned)NSEQ) ? xb[a + 2] : 0.f;
                    v.w = ((unsigned)(a + 3) < (unsigned)NSEQ) ? xb[a + 3] : 0.f;
                }
                const int jo = 2 * q - 2;
                const int je = 2 * q - 1;
                if ((unsigned)jo       < 2300u) bufA[2304 + jo]     = v.x;  // O[2q-2]
                if ((unsigned)je       < 2300u) bufA[je]            = v.y;  // E[2q-1]
                if ((unsigned)(jo + 1) < 2300u) bufA[2304 + jo + 1] = v.z;  // O[2q-1]
                if ((unsigned)(je + 1) < 2300u) bufA[je + 1]        = v.w;  // E[2q]
            }
        }
    }
    __syncthreads();

    // ---- analysis L1..L5 (dual-task); task counts 287,286,284,280,272 ----
    analysis8<2304, 2296,  1, 16384, EDGE, 2296, 1148>(bufA, bufB, klh, bss + 0,  (s >> 1) - 109);
    __syncthreads();
    analysis8<1148, 1144,  2,  8192, EDGE, 1144,  572>(bufB, bufA, klh, bss + 2,  (s >> 2) - 53);
    __syncthreads();
    analysis8< 572,  568,  4,  4096, EDGE,  568,  284>(bufA, bufB, klh, bss + 6,  (s >> 3) - 25);
    __syncthreads();
    analysis8< 284,  280,  8,  2048, EDGE,  280,  140>(bufB, bufA, klh, bss + 14, (s >> 4) - 11);
    __syncthreads();
    analysis8< 140,  136, 16,  1024, EDGE,  136,    0, true>(bufA, bufB, klh, bss + 30, (s >> 5) - 4);
    __syncthreads();

    // ---- synthesis s5..s2 (dual-task + tail); task counts 528,520,516,514 ----
    synthN< 136,  264, 16,  2048, EDGE>(bufB, bufA, lrev, hrev, (s >> 4) - 4);   // L5 -> r4
    __syncthreads();
    synthN< 264,  520,  8,  4096, EDGE>(bufA, bufB, lrev, hrev, (s >> 3) - 4);   // r4 -> r3
    __syncthreads();
    synthN< 520, 1032,  4,  8192, EDGE>(bufB, bufA, lrev, hrev, (s >> 2) - 4);   // r3 -> r2
    __syncthreads();
    synthN<1032, 2056,  2, 16384, EDGE>(bufA, bufB, lrev, hrev, (s >> 1) - 4);   // r2 -> r1
    __syncthreads();

    // ---- final level (G=1) to global; r1 in bufB stride 2056; 512 tasks x 8, dual ----
    {
#pragma unroll
        for (int k = 0; k < 2; ++k) {
            const int t  = tid + TPB * k;
            const int i0 = t * 8;
            float ya[12], yb[12];
            const float* p0 = bufB + i0 / 2;          // channel 0 = lp (16B aligned)
            ld12(ya, p0);
            ld12(yb, p0 + 2056);
            float o[8];
            synth_core<2, false>(ya, yb, lrev, hrev, 0, 1 << 30, o);
            stf4(ob + i0,     make_float4(o[0], o[1], o[2], o[3]));
            stf4(ob + i0 + 4, make_float4(o[4], o[5], o[6], o[7]));
        }
    }
}

__global__ __launch_bounds__(TPB, 4) void wpt_fused(
    const float* __restrict__ x,
    const float* __restrict__ K1, const float* __restrict__ K2,
    const float* __restrict__ K3, const float* __restrict__ K4,
    const float* __restrict__ K5,
    const float* __restrict__ B1, const float* __restrict__ B2,
    const float* __restrict__ B3, const float* __restrict__ B4,
    const float* __restrict__ B5,
    float* __restrict__ out)
{
    __shared__ __align__(16) float bufA[4608];
    __shared__ __align__(16) float bufB[4608];
    __shared__ float bss[62];

    const int tid   = threadIdx.x;
    const int batch = blockIdx.x >> 3;
    const int cid   = blockIdx.x & 7;
    const int s     = cid * C0;

    // Filters in SGPRs: K1 = [lp | hp]; every level's rows are one of these two.
    float lp[8], hp[8];
#pragma unroll
    for (int t = 0; t < 8; ++t) {
        lp[t] = rfl(K1[t]);
        hp[t] = rfl(K1[8 + t]);
    }
    // Packed coefficient tables for pk_fma paths.
    f2 klh[8], lrev[4], hrev[4];
#pragma unroll
    for (int t = 0; t < 8; ++t) klh[t] = (f2){lp[t], hp[t]};
#pragma unroll
    for (int q = 0; q < 4; ++q) {
        lrev[q] = (f2){lp[6 - 2 * q], lp[7 - 2 * q]};
        hrev[q] = (f2){hp[6 - 2 * q], hp[7 - 2 * q]};
    }

    // Biases (pre-scaled by 10*log2(e)); 62 total
    {
        const float* bin[5] = {B1, B2, B3, B4, B5};
        const int boff[5] = {0, 2, 6, 14, 30};
#pragma unroll
        for (int l = 0; l < 5; ++l)
            for (int i = tid; i < (2 << l); i += TPB) bss[boff[l] + i] = SCG * bin[l][i];
    }

    const float* xb = x + batch * NSEQ;
    float* ob = out + batch * NSEQ + s;

    if (cid == 0 || cid == 7)
        run_chunk<true >(xb, ob, s, bufA, bufB, klh, lrev, hrev, bss);
    else
        run_chunk<false>(xb, ob, s, bufA, bufB, klh, lrev, hrev, bss);
}

extern "C" void kernel_launch(void* const* d_in, const int* in_sizes, int n_in,
                              void* d_out, int out_size, void* d_ws, size_t ws_size,
                              hipStream_t stream) {
    const int nbatch = in_sizes[0] / NSEQ;
    wpt_fused<<<dim3(nbatch * (NSEQ / C0)), dim3(TPB), 0, stream>>>(
        (const float*)d_in[0],
        (const float*)d_in[1], (const float*)d_in[2],
        (const float*)d_in[3], (const float*)d_in[4],
        (const float*)d_in[5],
        (const float*)d_in[6], (const float*)d_in[7],
        (const float*)d_in[8], (const float*)d_in[9],
        (const float*)d_in[10],
        (float*)d_out);
}